// Round 4
// baseline (103.406 us; speedup 1.0000x reference)
//
#include <hip/hip_runtime.h>
#include <math.h>

#define OUT_NUM 1024
#define LUT_NUM 64
#define TBL     64
#define WSTRIDE 68              // row stride: 16B-aligned (68*4=272), banks 2-way (free)
#define XROW    (LUT_NUM * 6)   // 384 floats of x per (br, o)
#define BR_TOT  32

// (tanh(v)+1)/2 == sigmoid(2v) = 1/(1+exp(-2v)); rel err ~1e-6, threshold 1.8e-2.
// Saturates correctly at +/-inf.
__device__ __forceinline__ float softbit(float v) {
    return __builtin_amdgcn_rcpf(1.0f + __expf(-2.0f * v));
}

// Thread = (rg, lut, h): h in 0..3 owns table entries [16h,16h+16) -> 16 VGPRs,
// computes tree levels 0-3 locally, levels 4-5 via shfl_xor(1)/(2) butterflies.
// (512,8): cap 64 VGPR -> 8 waves/SIMD -> 32 waves/CU -> 4 blocks/CU ->
// all 1024 blocks resident in one round at FULL occupancy.
__global__ __launch_bounds__(512, 8)
void lut_fwd_kernel(const float* __restrict__ x,
                    const float* __restrict__ w,
                    float* __restrict__ out)
{
    __shared__ float wq[LUT_NUM * WSTRIDE];   // per lut row: [0..31]=evn, [32..63]=dif

    const int o = blockIdx.x;       // 0..1023
    const int t = threadIdx.x;      // 0..511

    // ---- Phase 1: stage w[o,:,:] (4096 floats), quantize, split (evn, dif) ----
    const float4* wrow4 = reinterpret_cast<const float4*>(w + (size_t)o * (LUT_NUM * TBL));
#pragma unroll
    for (int i = 0; i < 2; ++i) {
        const int f4 = t + 512 * i;        // 0..1023, coalesced
        const float4 v = wrow4[f4];
        const int f    = f4 * 4;           // flat float index (mult of 4)
        const int lutc = f >> 6;
        const int p    = (f & 63) >> 1;    // even pair index
        const float s0 = softbit(v.x);
        const float s1 = softbit(v.y);
        const float s2 = softbit(v.z);
        const float s3 = softbit(v.w);
        float* row = &wq[lutc * WSTRIDE];
        row[p]      = s0;
        row[32 + p] = s1 - s0;             // level-0 diff precomputed
        row[p + 1]  = s2;
        row[33 + p] = s3 - s2;
    }
    __syncthreads();

    const int h   = t & 3;           // tree-quarter replica (lane quad)
    const int lut = (t >> 2) & 63;   // which LUT
    const int rg  = t >> 8;          // row group: waves 0-3 -> br 0..15, 4-7 -> 16..31

    // ---- this thread's 16 table entries: evn/dif[8h..8h+7] (4x ds_read_b128) ----
    const float* row = &wq[lut * WSTRIDE + 8 * h];
    float evn[8], dif[8];
#pragma unroll
    for (int i = 0; i < 8; ++i) { evn[i] = row[i]; dif[i] = row[32 + i]; }

    const float* xb = x + (size_t)o * XROW + lut * 6;      // 8B-aligned (lut*6 even)
    float* ob = out + (size_t)o * LUT_NUM + lut;
    const bool writer = (h == 0);

    // ---- Phase 2: 16 rows per thread ----
#pragma unroll 2
    for (int j = 0; j < 16; ++j) {
        const int br = rg * 16 + j;  // 0..31
        const float2* xp = reinterpret_cast<const float2*>(xb + (size_t)br * (OUT_NUM * XROW));
        const float2 p01 = xp[0];
        const float2 p23 = xp[1];
        const float2 p45 = xp[2];

        // levels 0-3 local (owned entries 16h..16h+15 -> y3[h])
        float z0[8];
#pragma unroll
        for (int i = 0; i < 8; ++i) z0[i] = fmaf(p01.x, dif[i], evn[i]);
        float z1[4];
#pragma unroll
        for (int i = 0; i < 4; ++i) z1[i] = fmaf(p01.y, z0[2*i+1] - z0[2*i], z0[2*i]);
        float z2[2];
#pragma unroll
        for (int i = 0; i < 2; ++i) z2[i] = fmaf(p23.x, z1[2*i+1] - z1[2*i], z1[2*i]);
        float z = fmaf(p23.y, z2[1] - z2[0], z2[0]);       // = y3[h]

        // level 4: pair (y3[2i], y3[2i+1]) -> partner lane h^1
        float pt = __shfl_xor(z, 1);
        float lo = (h & 1) ? pt : z;
        float hi = (h & 1) ? z  : pt;
        z = fmaf(p45.x, hi - lo, lo);                      // = y4[h>>1] (all 4 lanes)

        // level 5: pair (y4[0], y4[1]) -> partner lane h^2
        pt = __shfl_xor(z, 2);
        lo = (h & 2) ? pt : z;
        hi = (h & 2) ? z  : pt;
        z = fmaf(p45.y, hi - lo, lo);                      // final (all 4 lanes)

        if (writer)
            ob[(size_t)br * (OUT_NUM * LUT_NUM)] = z;      // 16 lanes/wave, 64B contig
    }
}

extern "C" void kernel_launch(void* const* d_in, const int* in_sizes, int n_in,
                              void* d_out, int out_size, void* d_ws, size_t ws_size,
                              hipStream_t stream)
{
    const float* x   = (const float*)d_in[0];   // [16,2,1024,384] f32
    const float* w   = (const float*)d_in[1];   // [1024,64,64]    f32
    float*       out = (float*)d_out;           // [16,2,1024,64]  f32
    lut_fwd_kernel<<<OUT_NUM, 512, 0, stream>>>(x, w, out);
}